// Round 6
// baseline (353.200 us; speedup 1.0000x reference)
//
#include <hip/hip_runtime.h>

#define N_DIM 32
#define C_IN 64
#define C_OUT 64
#define T_DIM 288
#define V_DIM 25
#define TV 7200              // T_DIM * V_DIM
#define NTV 230400           // N_DIM * TV  (BN reduction count per channel)
#define TOTAL 14745600       // N_DIM * C_OUT * TV == N*C_IN*T*V (agg size too)
#define BN_EPS 1e-5f
#define NTILES 1800          // NTV / 128

// ws layout (float offsets)
#define WS_WINT 0            // wint[half][c][oo][2] : 2*64*32*2 = 8192 floats
#define WS_SUM 8192          // gsum[64]
#define WS_SQ  8256          // gsumsq[64]

// ---------------------------------------------------------------- K0: prep
__global__ __launch_bounds__(256) void prep_kernel(const float* __restrict__ W,
                                                   float* __restrict__ ws) {
  const int i = blockIdx.x * 256 + threadIdx.x;   // 0..8191
  if (blockIdx.x == 0 && threadIdx.x < 128) ws[WS_SUM + threadIdx.x] = 0.0f;
  // i = ((h*64 + c)*32 + oo)*2 + s
  const int s = i & 1;
  const int oo = (i >> 1) & 31;
  const int c = (i >> 6) & 63;
  const int h = i >> 12;
  const int o = h * 32 + oo;
  ws[WS_WINT + i] = W[o * 128 + s * 64 + c];  // s=0: fv weight, s=1: agg weight
}

// ---------------------------------------------------------------- K1: agg
// agg[n,c,t,y] = sum_v fv[n,c,t,v] * adj[v,y]; written into d_out (scratch).
__global__ __launch_bounds__(256) void agg_kernel(const float* __restrict__ fv,
                                                  const float* __restrict__ adj,
                                                  float* __restrict__ aggout) {
  const int e = blockIdx.x * 256 + threadIdx.x;   // 0..TOTAL-1 (exact grid)
  const int r = e / V_DIM;                        // row (n,c,t)
  const int y = e - r * V_DIM;
  const float* __restrict__ p = fv + r * V_DIM;   // 25 row values (L1-shared)
  float a0 = 0.f, a1 = 0.f, a2 = 0.f, a3 = 0.f;
#pragma unroll
  for (int v = 0; v < 24; v += 4) {
    a0 = fmaf(p[v + 0], adj[(v + 0) * V_DIM + y], a0);
    a1 = fmaf(p[v + 1], adj[(v + 1) * V_DIM + y], a1);
    a2 = fmaf(p[v + 2], adj[(v + 2) * V_DIM + y], a2);
    a3 = fmaf(p[v + 3], adj[(v + 3) * V_DIM + y], a3);
  }
  a0 = fmaf(p[24], adj[24 * V_DIM + y], a0);
  aggout[e] = (a0 + a1) + (a2 + a3);
}

// butterfly-transpose reduce: v[32] per lane (destroyed); every lane returns
// the sum of element (lane&31) across its 32-lane group.
__device__ __forceinline__ float reduce32_lane(float* v, int lane) {
#pragma unroll
  for (int s = 0; s < 5; ++s) {
    const int m = 1 << s;
    const bool up = (lane & m) != 0;
    const int pairs = 32 >> (s + 1);
#pragma unroll
    for (int q = 0; q < pairs; ++q) {
      const float keep = up ? v[2 * q + 1] : v[2 * q];
      const float send = up ? v[2 * q] : v[2 * q + 1];
      const float recv = __shfl_xor(send, m, 64);
      v[q] = keep + recv;
    }
  }
  return v[0];
}

// ---------------------------------------------------------------- K2: conv
// 256 threads = 128 columns x 2 channel-halves. Streaming coalesced reads of
// fv and agg (agg lives in d_out); overwrites d_out with pre-BN conv result.
// Safe: each block's agg-read addresses == its out-write addresses (same 128
// columns), separated by one __syncthreads; blocks own disjoint columns.
__global__ __launch_bounds__(256, 6) void conv_kernel(
    const float* __restrict__ fv, const float* __restrict__ wint,
    float* __restrict__ stats, float* __restrict__ out) {
  __shared__ float lsum[C_OUT];
  __shared__ float lsq[C_OUT];
  const int tid = threadIdx.x;
  if (tid < 64) { lsum[tid] = 0.0f; lsq[tid] = 0.0f; }
  __syncthreads();

  // wave-uniform channel-half selector (keeps weight address scalar -> s_load;
  // losing this was the R2 3x regression)
  const int half = __builtin_amdgcn_readfirstlane(tid) >> 7;
  const int lane = tid & 63;
  const float* __restrict__ wbase = wint + half * 4096;

  const int j = (blockIdx.x << 7) + (tid & 127);  // global column 0..NTV-1
  const int n = j / TV;
  const int rem = j - n * TV;                     // (t,y) combined, contiguous
  const int base = n * (C_IN * TV) + rem;         // + c*TV per channel

  float acc[32];
#pragma unroll
  for (int oo = 0; oo < 32; ++oo) acc[oo] = 0.0f;

#pragma unroll 4
  for (int c = 0; c < C_IN; ++c) {
    const float x = fv[base + c * TV];            // coalesced stream
    const float xa = out[base + c * TV];          // coalesced stream (agg)
    const float* __restrict__ w = wbase + c * 64; // wave-uniform -> s_load
#pragma unroll
    for (int oo = 0; oo < 32; ++oo)
      acc[oo] = fmaf(x, w[oo * 2], fmaf(xa, w[oo * 2 + 1], acc[oo]));
  }

  __syncthreads();   // all agg reads in this block complete before overwrite

  // write pre-BN output (channels half*32 .. half*32+31)
  float* op = out + base + (size_t)(half * 32) * TV;
#pragma unroll
  for (int oo = 0; oo < 32; ++oo) op[oo * TV] = acc[oo];

  // per-wave channel sums / sumsq -> LDS -> one global atomic set per block
  float sq[32];
#pragma unroll
  for (int i = 0; i < 32; ++i) sq[i] = acc[i] * acc[i];
  float s = reduce32_lane(acc, lane);             // destroys acc
  s += __shfl_xor(s, 32, 64);
  float q = reduce32_lane(sq, lane);
  q += __shfl_xor(q, 32, 64);

  if (lane < 32) {
    atomicAdd(&lsum[half * 32 + lane], s);
    atomicAdd(&lsq[half * 32 + lane], q);
  }
  __syncthreads();
  if (tid < 64) {
    atomicAdd(&stats[tid], lsum[tid]);
    atomicAdd(&stats[64 + tid], lsq[tid]);
  }
}

// ---------------------------------------------------------------- K3: BN+ReLU
// one block per (n, o) slab of TV floats; channel index is scalar.
__global__ __launch_bounds__(256) void bn_kernel(const float* __restrict__ stats,
                                                 const float* __restrict__ gamma,
                                                 const float* __restrict__ beta,
                                                 float* __restrict__ out) {
  const int o = blockIdx.x & 63;                  // out[n, o, t, y]
  const float inv = 1.0f / (float)NTV;
  const float mean = stats[o] * inv;
  const float var = fmaf(stats[64 + o], inv, -mean * mean);
  const float sc = gamma[o] * rsqrtf(var + BN_EPS);
  const float sh = fmaf(-mean, sc, beta[o]);

  float4* base = reinterpret_cast<float4*>(out) + (size_t)blockIdx.x * 1800;
#pragma unroll 1
  for (int i = threadIdx.x; i < 1800; i += 256) {  // 1800 = TV/4
    float4 v = base[i];
    v.x = fmaxf(fmaf(v.x, sc, sh), 0.0f);
    v.y = fmaxf(fmaf(v.y, sc, sh), 0.0f);
    v.z = fmaxf(fmaf(v.z, sc, sh), 0.0f);
    v.w = fmaxf(fmaf(v.w, sc, sh), 0.0f);
    base[i] = v;
  }
}

// ---------------------------------------------------------------- launcher
extern "C" void kernel_launch(void* const* d_in, const int* in_sizes, int n_in,
                              void* d_out, int out_size, void* d_ws, size_t ws_size,
                              hipStream_t stream) {
  const float* fv = (const float*)d_in[0];
  const float* adj = (const float*)d_in[1];
  const float* W = (const float*)d_in[2];
  // d_in[3] = b : exactly cancelled by training-mode BN mean subtraction
  const float* gamma = (const float*)d_in[4];
  const float* beta = (const float*)d_in[5];
  float* out = (float*)d_out;
  float* ws = (float*)d_ws;

  hipLaunchKernelGGL(prep_kernel, dim3(32), dim3(256), 0, stream, W, ws);
  // agg -> d_out (scratch; same element count as the final output)
  hipLaunchKernelGGL(agg_kernel, dim3(TOTAL / 256), dim3(256), 0, stream,
                     fv, adj, out);
  hipLaunchKernelGGL(conv_kernel, dim3(NTILES), dim3(256), 0, stream,
                     fv, ws + WS_WINT, ws + WS_SUM, out);
  hipLaunchKernelGGL(bn_kernel, dim3(N_DIM * C_OUT), dim3(256), 0, stream,
                     ws + WS_SUM, gamma, beta, out);
}

// Round 8
// 286.420 us; speedup vs baseline: 1.2332x; 1.2332x over previous
//
#include <hip/hip_runtime.h>

#define N_DIM 32
#define C_IN 64
#define C_OUT 64
#define T_DIM 288
#define V_DIM 25
#define TV 7200              // T_DIM * V_DIM
#define NROWS 9216           // N_DIM * T_DIM
#define NTV 230400           // N_DIM * TV  (BN reduction count per channel)
#define TOTAL 14745600       // N_DIM * C_OUT * TV
#define BN_EPS 1e-5f
#define NTILES 1800          // NTV / 128

// LDS slab geometry: per channel 7 rows x 28 words (25 data + 3 pad; 28%4==0
// keeps every row 16B-aligned for ds_read_b128; stride 28 mod 32 spreads rows
// across banks). Slab = 196 words; total 64*196*4 = 50,176 B -> 3 blocks/CU.
#define ROW_W 28
#define SLAB_W 196

// ws layout (float offsets)
#define WS_WINT 0            // wint[half][c][oo][2] : 2*64*32*2 = 8192 floats
#define WS_SUM 8192          // gsum[64]
#define WS_SQ  8256          // gsumsq[64]

// ---------------------------------------------------------------- K0: prep
__global__ __launch_bounds__(256) void prep_kernel(const float* __restrict__ W,
                                                   float* __restrict__ ws) {
  const int i = blockIdx.x * 256 + threadIdx.x;   // 0..8191
  if (blockIdx.x == 0 && threadIdx.x < 128) ws[WS_SUM + threadIdx.x] = 0.0f;
  // i = ((h*64 + c)*32 + oo)*2 + s
  const int s = i & 1;
  const int oo = (i >> 1) & 31;
  const int c = (i >> 6) & 63;
  const int h = i >> 12;
  const int o = h * 32 + oo;
  ws[WS_WINT + i] = W[o * 128 + s * 64 + c];  // s=0: fv weight, s=1: agg weight
}

// butterfly-transpose reduce: v[32] per lane (destroyed); every lane returns
// the sum of element (lane&31) across its 32-lane group.
__device__ __forceinline__ float reduce32_lane(float* v, int lane) {
#pragma unroll
  for (int s = 0; s < 5; ++s) {
    const int m = 1 << s;
    const bool up = (lane & m) != 0;
    const int pairs = 32 >> (s + 1);
#pragma unroll
    for (int q = 0; q < pairs; ++q) {
      const float keep = up ? v[2 * q + 1] : v[2 * q];
      const float send = up ? v[2 * q] : v[2 * q + 1];
      const float recv = __shfl_xor(send, m, 64);
      v[q] = keep + recv;
    }
  }
  return v[0];
}

// ---------------------------------------------------------------- K1: fused
// 256 threads = 128 columns x 2 channel-halves; one 128-col tile per block.
// Stage ALL 64 channels of the tile's <=7 rows into LDS once (coalesced, one
// barrier), then agg+conv+stats entirely from LDS / s_load weights.
__global__ __launch_bounds__(256, 3) void fused_kernel(
    const float* __restrict__ fv, const float* __restrict__ adj,
    const float* __restrict__ wint, float* __restrict__ stats,
    float* __restrict__ out) {
  __shared__ __align__(16) float lfv[C_IN * SLAB_W];   // 50,176 B
  __shared__ float lsum[C_OUT];
  __shared__ float lsq[C_OUT];

  const int tid = threadIdx.x;
  if (tid < 64) { lsum[tid] = 0.0f; lsq[tid] = 0.0f; }

  // wave-uniform channel-half selector (keeps weight address scalar -> s_load;
  // losing this was the R2 3x regression)
  const int half = __builtin_amdgcn_readfirstlane(tid) >> 7;
  const int lane = tid & 63;
  const float* __restrict__ wbase = wint + half * 4096;

  const int j0 = blockIdx.x << 7;
  const int rbase = j0 / V_DIM;
  const int col = j0 + (tid & 127);
  const int row = col / V_DIM;              // n*T + t
  const int y = col - row * V_DIM;
  const int rowoff = row - rbase;           // 0..6

  // adjacency column for this thread's joint
  float adjcol[V_DIM];
#pragma unroll
  for (int v = 0; v < V_DIM; ++v) adjcol[v] = adj[v * V_DIM + y];

  // ---- stage: 64 ch x <=7 rows x 25 joints, coalesced 25-float runs ----
#pragma unroll 1
  for (int i = tid; i < C_IN * 175; i += 256) {
    const int c = i / 175;
    const int rem = i - c * 175;
    const int rr = rem / V_DIM;
    const int v = rem - rr * V_DIM;
    const int Rg = rbase + rr;
    float val = 0.0f;
    if (Rg < NROWS) {
      const int n = Rg / T_DIM;
      const int t = Rg - n * T_DIM;
      val = fv[n * (C_IN * TV) + c * TV + t * V_DIM + v];
    }
    lfv[c * SLAB_W + rr * ROW_W + v] = val;
  }
  __syncthreads();

  // ---- compute: all from LDS ----
  float acc[32];
#pragma unroll
  for (int oo = 0; oo < 32; ++oo) acc[oo] = 0.0f;

#pragma unroll 1
  for (int c = 0; c < C_IN; ++c) {
    const float* __restrict__ br = &lfv[c * SLAB_W + rowoff * ROW_W];
    const float x = br[y];                         // stride-1 across lanes
    const float4* __restrict__ b4 = reinterpret_cast<const float4*>(br);
    float xa0 = 0.f, xa1 = 0.f, xa2 = 0.f, xa3 = 0.f;
#pragma unroll
    for (int q = 0; q < 6; ++q) {
      const float4 f = b4[q];                      // aligned, bank-distinct
      xa0 = fmaf(f.x, adjcol[4 * q + 0], xa0);
      xa1 = fmaf(f.y, adjcol[4 * q + 1], xa1);
      xa2 = fmaf(f.z, adjcol[4 * q + 2], xa2);
      xa3 = fmaf(f.w, adjcol[4 * q + 3], xa3);
    }
    xa0 = fmaf(br[24], adjcol[24], xa0);
    const float xa = (xa0 + xa1) + (xa2 + xa3);

    // 64 contiguous wave-uniform floats -> s_load + SGPR-operand fma
    const float* __restrict__ w = wbase + c * 64;
#pragma unroll
    for (int oo = 0; oo < 32; ++oo)
      acc[oo] = fmaf(x, w[oo * 2], fmaf(xa, w[oo * 2 + 1], acc[oo]));
  }

  // ---- write pre-BN output (channels half*32 .. half*32+31) ----
  {
    const int n = row / T_DIM;
    const int t = row - n * T_DIM;
    float* op = out + ((size_t)n * C_OUT + half * 32) * TV + t * V_DIM + y;
#pragma unroll
    for (int oo = 0; oo < 32; ++oo) op[oo * TV] = acc[oo];   // coalesced/oo
  }

  // ---- per-wave channel sums / sumsq -> LDS -> one global atomic set ----
  float sq[32];
#pragma unroll
  for (int i = 0; i < 32; ++i) sq[i] = acc[i] * acc[i];
  float s = reduce32_lane(acc, lane);              // destroys acc
  s += __shfl_xor(s, 32, 64);
  float q = reduce32_lane(sq, lane);
  q += __shfl_xor(q, 32, 64);

  if (lane < 32) {
    atomicAdd(&lsum[half * 32 + lane], s);
    atomicAdd(&lsq[half * 32 + lane], q);
  }
  __syncthreads();
  if (tid < 64) {
    atomicAdd(&stats[tid], lsum[tid]);
    atomicAdd(&stats[64 + tid], lsq[tid]);
  }
}

// ---------------------------------------------------------------- K2: BN+ReLU
// one block per (n, o) slab of TV floats; channel index is scalar.
__global__ __launch_bounds__(256) void bn_kernel(const float* __restrict__ stats,
                                                 const float* __restrict__ gamma,
                                                 const float* __restrict__ beta,
                                                 float* __restrict__ out) {
  const int o = blockIdx.x & 63;                  // out[n, o, t, y]
  const float inv = 1.0f / (float)NTV;
  const float mean = stats[o] * inv;
  const float var = fmaf(stats[64 + o], inv, -mean * mean);
  const float sc = gamma[o] * rsqrtf(var + BN_EPS);
  const float sh = fmaf(-mean, sc, beta[o]);

  float4* base = reinterpret_cast<float4*>(out) + (size_t)blockIdx.x * 1800;
#pragma unroll 1
  for (int i = threadIdx.x; i < 1800; i += 256) {  // 1800 = TV/4
    float4 v = base[i];
    v.x = fmaxf(fmaf(v.x, sc, sh), 0.0f);
    v.y = fmaxf(fmaf(v.y, sc, sh), 0.0f);
    v.z = fmaxf(fmaf(v.z, sc, sh), 0.0f);
    v.w = fmaxf(fmaf(v.w, sc, sh), 0.0f);
    base[i] = v;
  }
}

// ---------------------------------------------------------------- launcher
extern "C" void kernel_launch(void* const* d_in, const int* in_sizes, int n_in,
                              void* d_out, int out_size, void* d_ws, size_t ws_size,
                              hipStream_t stream) {
  const float* fv = (const float*)d_in[0];
  const float* adj = (const float*)d_in[1];
  const float* W = (const float*)d_in[2];
  // d_in[3] = b : exactly cancelled by training-mode BN mean subtraction
  const float* gamma = (const float*)d_in[4];
  const float* beta = (const float*)d_in[5];
  float* out = (float*)d_out;
  float* ws = (float*)d_ws;

  hipLaunchKernelGGL(prep_kernel, dim3(32), dim3(256), 0, stream, W, ws);
  hipLaunchKernelGGL(fused_kernel, dim3(NTILES), dim3(256), 0, stream,
                     fv, adj, ws + WS_WINT, ws + WS_SUM, out);
  hipLaunchKernelGGL(bn_kernel, dim3(N_DIM * C_OUT), dim3(256), 0, stream,
                     ws + WS_SUM, gamma, beta, out);
}